// Round 3
// baseline (4620.096 us; speedup 1.0000x reference)
//
#include <hip/hip_runtime.h>

#define T_STEPS 2048
#define BATCH   64
#define IN_DIM  256
#define HID     512

typedef _Float16 half_t;
typedef half_t half2_t __attribute__((ext_vector_type(2)));
typedef _Float16 f16x8 __attribute__((ext_vector_type(8)));
typedef float f32x4 __attribute__((ext_vector_type(4)));

#if __has_builtin(__builtin_amdgcn_fdot2)
__device__ __forceinline__ float fdot2(half2_t a, half2_t b, float c) {
    return __builtin_amdgcn_fdot2(a, b, c, false);   // v_dot2_f32_f16
}
#else
__device__ __forceinline__ float fdot2(half2_t a, half2_t b, float c) {
    return c + (float)a.x * (float)b.x + (float)a.y * (float)b.y;
}
#endif

// 16B bundle of 4 half2 pairs -> ds_read_b128 / ds_write_b128.
struct alignas(16) h2x4 { half2_t v[4]; };

// ---------------------------------------------------------------------------
// K1: x_proj[t*B+b][h] = input[t*B+b][i] @ w_in[i][h]   (unchanged)
// ---------------------------------------------------------------------------
__global__ __launch_bounds__(256, 4)
void xproj_gemm(const float* __restrict__ A, const float* __restrict__ Win,
                float* __restrict__ out) {
    __shared__ float As[32][132];
    __shared__ float Bs[32][132];
    const int tid = threadIdx.x;
    const int m0 = blockIdx.y * 128;
    const int n0 = blockIdx.x * 128;
    const int tm = (tid >> 4) << 3;
    const int tn = (tid & 15) << 3;

    float acc[8][8] = {};

    for (int k0 = 0; k0 < IN_DIM; k0 += 32) {
        {
            const int m  = tid >> 3;
            const int k4 = (tid & 7) << 2;
#pragma unroll
            for (int r = 0; r < 4; ++r) {
                const float4 a4 = *(const float4*)&A[(size_t)(m0 + m + 32 * r) * IN_DIM + k0 + k4];
                As[k4 + 0][m + 32 * r] = a4.x;
                As[k4 + 1][m + 32 * r] = a4.y;
                As[k4 + 2][m + 32 * r] = a4.z;
                As[k4 + 3][m + 32 * r] = a4.w;
            }
        }
        {
            const int kb = tid >> 5;
            const int n4 = (tid & 31) << 2;
#pragma unroll
            for (int r = 0; r < 4; ++r) {
                const float4 b4 = *(const float4*)&Win[(size_t)(k0 + kb + 8 * r) * HID + n0 + n4];
                *(float4*)&Bs[kb + 8 * r][n4] = b4;
            }
        }
        __syncthreads();
#pragma unroll
        for (int kk = 0; kk < 32; ++kk) {
            const float4 a0 = *(const float4*)&As[kk][tm];
            const float4 a1 = *(const float4*)&As[kk][tm + 4];
            const float4 b0 = *(const float4*)&Bs[kk][tn];
            const float4 b1 = *(const float4*)&Bs[kk][tn + 4];
            const float av[8] = {a0.x, a0.y, a0.z, a0.w, a1.x, a1.y, a1.z, a1.w};
            const float bv[8] = {b0.x, b0.y, b0.z, b0.w, b1.x, b1.y, b1.z, b1.w};
#pragma unroll
            for (int i = 0; i < 8; ++i)
#pragma unroll
                for (int j = 0; j < 8; ++j)
                    acc[i][j] = fmaf(av[i], bv[j], acc[i][j]);
        }
        __syncthreads();
    }

#pragma unroll
    for (int i = 0; i < 8; ++i) {
        float4 c0 = {acc[i][0], acc[i][1], acc[i][2], acc[i][3]};
        float4 c1 = {acc[i][4], acc[i][5], acc[i][6], acc[i][7]};
        float* dst = &out[(size_t)(m0 + tm + i) * HID + n0 + tn];
        *(float4*)dst       = c0;
        *(float4*)(dst + 4) = c1;
    }
}

// ---------------------------------------------------------------------------
// K2: sequential scan, hybrid VALU+MFMA. 64 WGs (1/batch), 512 thr (8 waves).
// Arch file = 256/waves_per_EU (measured r0/r1/r2: 128@8w, 64@16w), so W can
// never be all-arch (384KB > 256KB arch/CU). Fix: the overflow lives in the
// ACC file as MFMA B-fragments (MFMA reads AGPRs natively -> zero copies).
//   VALU part, k in [0,256): wave kg owns k [32kg,32kg+32) x all 512 cols.
//     W: pairs [0,8) in 64 arch regs; pairs [8,16) in two 64KB LDS slabs
//     (b128, conflict-free). h chunks: uniform 16B broadcasts. -> parts[8][].
//   MFMA part, k in [256,512): wave kg owns cols [64kg,64kg+64) (4 16x16
//     tiles) x all 256 k (8 kblocks). W: bfrag[4][8] f16x8 = 128 regs ->
//     acc file exactly. A-operand: every 16-lane group broadcast-reads the
//     SAME 16B of h, so all 16 A rows = h; every D row equals the output and
//     the k-sum is layout-permutation-invariant (A,B share (lane,elem)->k).
//     D col = lane&15 (m89-verified) -> lanes<16 write parts_m[512].
//   Finalize: s = xp + 8 VALU partials + 1 MFMA partial; tanh; f16 h update.
//   Barrier2 is raw lgkmcnt-only s_barrier: out[] stores float across steps
//   (no per-step vmcnt(0) drain).
// ---------------------------------------------------------------------------
__global__ __attribute__((amdgpu_flat_work_group_size(512, 512),
                          amdgpu_waves_per_eu(2, 2)))
void rnn_scan(const float* __restrict__ Wrec, float* __restrict__ out) {
    __shared__ h2x4  WA[8 * 512];     // 64 KB: VALU W pairs [8,12), slot c
    __shared__ h2x4  WB[8 * 512];     // 64 KB: VALU W pairs [12,16)
    __shared__ float parts[8 * 640];  // 20 KB: [kg][9*jg + c] skewed
    __shared__ float parts_m[512];    //  2 KB: MFMA partial per column
    __shared__ f16x8 h2raw[64];       //  1 KB: current h as 512 f16

    const int tid   = threadIdx.x;
    const int b     = blockIdx.x;
    const int jg    = tid & 63;
    const int kg    = tid >> 6;          // wave id
    const int col0  = jg << 3;           // 8 cols (VALU part)
    const int kbase = kg << 5;           // 32 k-rows (VALU part)
    const int lane  = tid & 63;

    // ---- VALU W: pairs [0,8) -> arch regs
    half2_t wreg[8][8];
#pragma unroll
    for (int p = 0; p < 8; ++p) {
        const int k = kbase + 2 * p;
        const float4 lo0 = *(const float4*)&Wrec[(size_t)k * HID + col0];
        const float4 lo1 = *(const float4*)&Wrec[(size_t)k * HID + col0 + 4];
        const float4 hi0 = *(const float4*)&Wrec[(size_t)(k + 1) * HID + col0];
        const float4 hi1 = *(const float4*)&Wrec[(size_t)(k + 1) * HID + col0 + 4];
        wreg[0][p].x = (half_t)lo0.x; wreg[0][p].y = (half_t)hi0.x;
        wreg[1][p].x = (half_t)lo0.y; wreg[1][p].y = (half_t)hi0.y;
        wreg[2][p].x = (half_t)lo0.z; wreg[2][p].y = (half_t)hi0.z;
        wreg[3][p].x = (half_t)lo0.w; wreg[3][p].y = (half_t)hi0.w;
        wreg[4][p].x = (half_t)lo1.x; wreg[4][p].y = (half_t)hi1.x;
        wreg[5][p].x = (half_t)lo1.y; wreg[5][p].y = (half_t)hi1.y;
        wreg[6][p].x = (half_t)lo1.z; wreg[6][p].y = (half_t)hi1.z;
        wreg[7][p].x = (half_t)lo1.w; wreg[7][p].y = (half_t)hi1.w;
    }
    // ---- VALU W: pairs [8,16) -> LDS slabs (16B bundles, lane-major)
#pragma unroll
    for (int q = 0; q < 2; ++q) {
        h2x4 bu[8];
#pragma unroll
        for (int pp = 0; pp < 4; ++pp) {
            const int k = kbase + 16 + 8 * q + 2 * pp;
            const float4 lo0 = *(const float4*)&Wrec[(size_t)k * HID + col0];
            const float4 lo1 = *(const float4*)&Wrec[(size_t)k * HID + col0 + 4];
            const float4 hi0 = *(const float4*)&Wrec[(size_t)(k + 1) * HID + col0];
            const float4 hi1 = *(const float4*)&Wrec[(size_t)(k + 1) * HID + col0 + 4];
            bu[0].v[pp].x = (half_t)lo0.x; bu[0].v[pp].y = (half_t)hi0.x;
            bu[1].v[pp].x = (half_t)lo0.y; bu[1].v[pp].y = (half_t)hi0.y;
            bu[2].v[pp].x = (half_t)lo0.z; bu[2].v[pp].y = (half_t)hi0.z;
            bu[3].v[pp].x = (half_t)lo0.w; bu[3].v[pp].y = (half_t)hi0.w;
            bu[4].v[pp].x = (half_t)lo1.x; bu[4].v[pp].y = (half_t)hi1.x;
            bu[5].v[pp].x = (half_t)lo1.y; bu[5].v[pp].y = (half_t)hi1.y;
            bu[6].v[pp].x = (half_t)lo1.z; bu[6].v[pp].y = (half_t)hi1.z;
            bu[7].v[pp].x = (half_t)lo1.w; bu[7].v[pp].y = (half_t)hi1.w;
        }
        h2x4* slab = q ? WB : WA;
#pragma unroll
        for (int c = 0; c < 8; ++c)
            slab[c * 512 + tid] = bu[c];
    }
    // ---- MFMA B-fragments: k in [256,512), wave kg's 4 col-tiles.
    // bfrag[tl][K] lane l: W[256+32K+8*((l>>4)&3)+i][64kg+16tl+(l&15)], i<8.
    const int lrow = tid & 15;
    const int lgrp = (tid >> 4) & 3;
    f16x8 bfrag[4][8];
#pragma unroll
    for (int tl = 0; tl < 4; ++tl)
#pragma unroll
        for (int K = 0; K < 8; ++K) {
            const int col = (kg << 6) + (tl << 4) + lrow;
            const int kb  = 256 + (K << 5) + (lgrp << 3);
            f16x8 f;
#pragma unroll
            for (int i = 0; i < 8; ++i)
                f[i] = (half_t)Wrec[(size_t)(kb + i) * HID + col];
            bfrag[tl][K] = f;
        }
    // h0 = 0
    if (tid < 64) {
        f16x8 z;
#pragma unroll
        for (int i = 0; i < 8; ++i) z[i] = (half_t)0.f;
        h2raw[tid] = z;
    }
    __syncthreads();

    const h2x4* hb4  = (const h2x4*)h2raw;
    const int jcol   = tid;
    const int pbase  = 9 * (jcol >> 3) + (jcol & 7);

    for (int t = 0; t < T_STEPS; ++t) {
        // prefetch xp (consumed at finalize; in flight across the math)
        const float xpv = out[((size_t)t * BATCH + b) * HID + jcol];

        // ---- MFMA part: k in [256,512). Broadcast-A: each 16-lane group
        // reads the same 16B of h -> all A rows = h -> all D rows = y.
        f32x4 d0 = {0.f, 0.f, 0.f, 0.f};
        f32x4 d1 = d0, d2 = d0, d3 = d0;
#pragma unroll
        for (int K = 0; K < 8; ++K) {
            const f16x8 af = h2raw[32 + (K << 2) + lgrp];
            d0 = __builtin_amdgcn_mfma_f32_16x16x32_f16(af, bfrag[0][K], d0, 0, 0, 0);
            d1 = __builtin_amdgcn_mfma_f32_16x16x32_f16(af, bfrag[1][K], d1, 0, 0, 0);
            d2 = __builtin_amdgcn_mfma_f32_16x16x32_f16(af, bfrag[2][K], d2, 0, 0, 0);
            d3 = __builtin_amdgcn_mfma_f32_16x16x32_f16(af, bfrag[3][K], d3, 0, 0, 0);
        }

        // ---- VALU part: k in [32kg, 32kg+32)
        float acc[8] = {};
#pragma unroll
        for (int j = 0; j < 2; ++j) {                    // pairs [0,8): arch
            const h2x4 hu = hb4[(kg << 2) + j];
#pragma unroll
            for (int pp = 0; pp < 4; ++pp)
#pragma unroll
                for (int c = 0; c < 8; ++c)
                    acc[c] = fdot2(wreg[c][4 * j + pp], hu.v[pp], acc[c]);
        }
        {                                                // pairs [8,12): WA
            const h2x4 hu = hb4[(kg << 2) + 2];
#pragma unroll
            for (int c = 0; c < 8; ++c) {
                const h2x4 wu = WA[c * 512 + tid];
#pragma unroll
                for (int pp = 0; pp < 4; ++pp)
                    acc[c] = fdot2(wu.v[pp], hu.v[pp], acc[c]);
            }
        }
        {                                                // pairs [12,16): WB
            const h2x4 hu = hb4[(kg << 2) + 3];
#pragma unroll
            for (int c = 0; c < 8; ++c) {
                const h2x4 wu = WB[c * 512 + tid];
#pragma unroll
                for (int pp = 0; pp < 4; ++pp)
                    acc[c] = fdot2(wu.v[pp], hu.v[pp], acc[c]);
            }
        }

        // ---- publish partials
#pragma unroll
        for (int c = 0; c < 8; ++c)
            parts[kg * 640 + 9 * jg + c] = acc[c];
        if (lane < 16) {                  // D col = lane&15 (m89), any row
            parts_m[(kg << 6) +  0 + lane] = d0[0];
            parts_m[(kg << 6) + 16 + lane] = d1[0];
            parts_m[(kg << 6) + 32 + lane] = d2[0];
            parts_m[(kg << 6) + 48 + lane] = d3[0];
        }
        __syncthreads();

        // ---- finalize column jcol
        float s = xpv + parts_m[jcol];
#pragma unroll
        for (int g = 0; g < 8; ++g)
            s += parts[g * 640 + pbase];
        const float e  = __expf(2.0f * s);
        const float hj = 1.0f - 2.0f / (e + 1.0f);     // tanh(s)

        out[((size_t)t * BATCH + b) * HID + jcol] = hj;
        if (t == T_STEPS - 1)
            out[(size_t)T_STEPS * BATCH * HID + (size_t)b * HID + jcol] = hj;

        ((half_t*)h2raw)[jcol] = (half_t)hj;
        // raw barrier: wait LDS only -- let the out[] store drain in the
        // background instead of serializing each step on vmcnt(0).
        asm volatile("s_waitcnt lgkmcnt(0)" ::: "memory");
        __builtin_amdgcn_s_barrier();
    }
}

extern "C" void kernel_launch(void* const* d_in, const int* in_sizes, int n_in,
                              void* d_out, int out_size, void* d_ws, size_t ws_size,
                              hipStream_t stream) {
    const float* A    = (const float*)d_in[0];   // [T,B,I]
    const float* Win  = (const float*)d_in[1];   // [I,H]
    const float* Wrec = (const float*)d_in[2];   // [H,H]
    float* out = (float*)d_out;                  // [T,B,H] hiddens ++ [B,H] h_last

    dim3 g1(HID / 128, (T_STEPS * BATCH) / 128); // (4, 1024)
    xproj_gemm<<<g1, 256, 0, stream>>>(A, Win, out);
    rnn_scan<<<BATCH, 512, 0, stream>>>(Wrec, out);
}